// Round 4
// baseline (106.132 us; speedup 1.0000x reference)
//
#include <hip/hip_runtime.h>

// B=32, C=8, L=2048, K=512, S=64, W=1985
// out[b,0,q] = max(0, max_w sum_c dot(xw_n[b,c,w,:], sn_n[c,q,:]) / 8)

#define B_ 32
#define C_ 8
#define L_ 2048
#define K_ 512
#define S_ 64
#define W_ 1985
#define TW 64                         // windows per block tile

typedef _Float16 f16x8 __attribute__((ext_vector_type(8)));
typedef float f32x4 __attribute__((ext_vector_type(4)));
typedef float f32x4u __attribute__((ext_vector_type(4), aligned(4)));

// ---- prologue: pack shapelets (blocks 0..127), window norms (blocks 128..383),
//      zero out (folded into norm blocks) ----
__global__ __launch_bounds__(256)
void prep_k(const float* __restrict__ x, const float* __restrict__ sh,
            _Float16* __restrict__ Bp, float* __restrict__ invn,
            float* __restrict__ out) {
    __shared__ float xr[L_];             // used by norm blocks only
    const int tid = threadIdx.x;
    const int blk = blockIdx.x;

    if (blk < 128) {
        // ---- pack: sn_norm fp16 in B-fragment order ----
        const int sb   = blk * 4 + (tid >> 6);   // 0..511 = c(8) x ks(2) x nt(32)
        const int c    = sb >> 6;
        const int ks   = (sb >> 5) & 1;
        const int nt   = sb & 31;
        const int lane = tid & 63;
        const int ncol = lane & 15, quad = lane >> 4;
        const int q    = nt * 16 + ncol;

        const float4* sp = (const float4*)(sh + (size_t)(c * K_ + q) * S_);
        float ss = 0.f;
        #pragma unroll
        for (int i = 0; i < 4; ++i) {
            float4 v = sp[quad * 4 + i];
            ss += v.x * v.x + v.y * v.y + v.z * v.z + v.w * v.w;
        }
        ss += __shfl_xor(ss, 16);
        ss += __shfl_xor(ss, 32);
        float inv = 1.f / fmaxf(sqrtf(ss), 1e-8f);

        float4 u0 = sp[ks * 8 + quad * 2];
        float4 u1 = sp[ks * 8 + quad * 2 + 1];
        f16x8 o;
        o[0] = (_Float16)(u0.x * inv); o[1] = (_Float16)(u0.y * inv);
        o[2] = (_Float16)(u0.z * inv); o[3] = (_Float16)(u0.w * inv);
        o[4] = (_Float16)(u1.x * inv); o[5] = (_Float16)(u1.y * inv);
        o[6] = (_Float16)(u1.z * inv); o[7] = (_Float16)(u1.w * inv);
        ((f16x8*)Bp)[((c * 2 + ks) * 32 + nt) * 64 + lane] = o;
    } else {
        // ---- window inverse norms for row r = b*8+c, sliding sum ----
        const int r = blk - 128;             // 0..255
        const float* xp = x + (size_t)r * L_;
        for (int i = tid; i < L_ / 4; i += 256)
            ((float4*)xr)[i] = ((const float4*)xp)[i];
        __syncthreads();

        float* ivp = invn + (size_t)r * L_;
        const int w0 = tid * 8;
        float ss = 0.f;
        if (w0 < W_) {
            #pragma unroll
            for (int j = 0; j < S_; ++j) { float v = xr[w0 + j]; ss += v * v; }
        }
        #pragma unroll
        for (int u = 0; u < 8; ++u) {
            int w = w0 + u;
            float o = 0.f;
            if (u > 0 && w < W_)
                ss += xr[w + 63] * xr[w + 63] - xr[w - 1] * xr[w - 1];
            if (w < W_) o = 0.125f / fmaxf(sqrtf(ss), 1e-8f);
            if (w < L_) ivp[w] = o;
        }
        if (r < 64) out[r * 256 + tid] = 0.f;   // zero output
    }
}

// ---- main: MFMA GEMM + relu + max ----
// grid (32 wt, 2 ng, 32 b) = 2048 blocks, 256 threads = 4 waves.
// wave wv: 64 windows (mt=4) x 64 cols (nt=4) at n-base ng*256 + wv*64.
// acc = 4x4x4 = 64 VGPRs. A-frags double-buffered in LDS, 1 barrier/channel.
__global__ __launch_bounds__(256, 3)
void mcs_k(const float* __restrict__ x, const _Float16* __restrict__ Bp,
           const float* __restrict__ invn, float* __restrict__ out) {
    __shared__ float invs[C_ * TW];      // 2 KB: 0.125/||window|| per (c,w)
    __shared__ f16x8 Ah[2][8 * 64];      // 16 KB: 8 frags (mt*2+ks) x 64 lanes

    const int wt  = blockIdx.x;
    const int ng  = blockIdx.y;
    const int b   = blockIdx.z;
    const int w0  = wt * TW;
    const int tid = threadIdx.x;
    const int lane = tid & 63;
    const int wv   = tid >> 6;
    const int quad = lane >> 4;

    // stage inv-norm slice
    for (int i = tid; i < C_ * TW; i += 256) {
        int c = i >> 6, w = i & 63;
        invs[i] = invn[(size_t)(b * C_ + c) * L_ + w0 + w];
    }

    // build channel cN's A-frags into Ah[bufN]; global reads, inv-scaled.
    // frag f=mt*2+ks, lane l=(row,qd): value[j] = x[c][w0+16mt+row+32ks+8qd+j]*inv
    auto build = [&](int cN, int bufN) {
        const float* xrow = x + (size_t)(b * C_ + cN) * L_;
        #pragma unroll
        for (int it = 0; it < 2; ++it) {
            int i   = tid + it * 256;
            int f   = i >> 6, l = i & 63;
            int mt  = f >> 1, ks = f & 1;
            int row = l & 15, qd = l >> 4;
            int m   = mt * 16 + row;
            int p   = w0 + m + ks * 32 + qd * 8;
            int pc  = p <= L_ - 8 ? p : L_ - 8;   // clamp: only invalid windows hit
            f32x4u v0 = *(const f32x4u*)(xrow + pc);
            f32x4u v1 = *(const f32x4u*)(xrow + pc + 4);
            float iv = invs[cN * TW + m];          // 0 for invalid windows
            f16x8 o;
            o[0] = (_Float16)(v0[0] * iv); o[1] = (_Float16)(v0[1] * iv);
            o[2] = (_Float16)(v0[2] * iv); o[3] = (_Float16)(v0[3] * iv);
            o[4] = (_Float16)(v1[0] * iv); o[5] = (_Float16)(v1[1] * iv);
            o[6] = (_Float16)(v1[2] * iv); o[7] = (_Float16)(v1[3] * iv);
            Ah[bufN][f * 64 + l] = o;
        }
    };

    __syncthreads();            // invs ready
    build(0, 0);
    __syncthreads();            // Ah[0] ready

    f32x4 acc[4][4];
    #pragma unroll
    for (int mt = 0; mt < 4; ++mt)
        #pragma unroll
        for (int nt = 0; nt < 4; ++nt)
            acc[mt][nt] = (f32x4){0.f, 0.f, 0.f, 0.f};

    #pragma unroll 2
    for (int c = 0; c < C_; ++c) {
        const int buf = c & 1;
        if (c + 1 < C_) build(c + 1, buf ^ 1);   // prefetch next channel

        #pragma unroll
        for (int ks = 0; ks < 2; ++ks) {
            f16x8 af[4], bf[4];
            const f16x8* bpp = (const f16x8*)Bp +
                ((c * 2 + ks) * 32 + ng * 16 + wv * 4) * 64 + lane;
            #pragma unroll
            for (int nt = 0; nt < 4; ++nt) bf[nt] = bpp[nt * 64];
            #pragma unroll
            for (int mt = 0; mt < 4; ++mt) af[mt] = Ah[buf][(mt * 2 + ks) * 64 + lane];
            #pragma unroll
            for (int nt = 0; nt < 4; ++nt)
                #pragma unroll
                for (int mt = 0; mt < 4; ++mt)
                    acc[mt][nt] = __builtin_amdgcn_mfma_f32_16x16x32_f16(
                        af[mt], bf[nt], acc[mt][nt], 0, 0, 0);
        }
        __syncthreads();        // consume(c) done + Ah[buf^1] written
    }

    // epilogue: relu + max over windows (invalid windows are exactly 0)
    // C/D layout: col = lane&15, row = quad*4 + r
    #pragma unroll
    for (int nt = 0; nt < 4; ++nt) {
        float m = 0.f;
        #pragma unroll
        for (int mt = 0; mt < 4; ++mt)
            #pragma unroll
            for (int r = 0; r < 4; ++r)
                m = fmaxf(m, acc[mt][nt][r]);
        m = fmaxf(m, __shfl_xor(m, 16));
        m = fmaxf(m, __shfl_xor(m, 32));
        if (lane < 16)
            atomicMax((unsigned int*)(out + b * K_ + ng * 256 + wv * 64 + nt * 16 + lane),
                      __float_as_uint(m));
    }
}

extern "C" void kernel_launch(void* const* d_in, const int* in_sizes, int n_in,
                              void* d_out, int out_size, void* d_ws, size_t ws_size,
                              hipStream_t stream) {
    const float* x  = (const float*)d_in[0];   // (32, 8, 2048) fp32
    const float* sh = (const float*)d_in[1];   // (8, 512, 64) fp32
    float* out = (float*)d_out;                // (32, 1, 512) fp32
    _Float16* Bp  = (_Float16*)d_ws;           // 512 KB packed shapelets
    float* invn   = (float*)((char*)d_ws + (size_t)K_ * 512 * sizeof(_Float16)); // 2 MB

    prep_k<<<dim3(384), dim3(256), 0, stream>>>(x, sh, Bp, invn, out);
    mcs_k<<<dim3(32, 2, B_), dim3(256), 0, stream>>>(x, Bp, invn, out);
}

// Round 5
// 100.748 us; speedup vs baseline: 1.0534x; 1.0534x over previous
//
#include <hip/hip_runtime.h>

// B=32, C=8, L=2048, K=512, S=64, W=1985
// out[b,0,q] = max(0, max_w sum_c dot(xw_n[b,c,w,:], sn_n[c,q,:]) / 8)

#define B_ 32
#define C_ 8
#define L_ 2048
#define K_ 512
#define S_ 64
#define W_ 1985
#define TW 64                         // windows per block tile

typedef _Float16 f16x8 __attribute__((ext_vector_type(8)));
typedef float f32x16 __attribute__((ext_vector_type(16)));
typedef float f32x4u __attribute__((ext_vector_type(4), aligned(4)));

// ---- prologue: pack shapelets (blocks 0..127) in 32x32x16 B-frag layout,
//      window inv-norms (blocks 128..383), zero out ----
// Bp unit ((c*4+kq)*16 + nt)*64 + lane:
//   value[j] = sn_norm[c][nt*32 + (lane&31)][kq*16 + (lane>>5)*8 + j]
__global__ __launch_bounds__(256)
void prep_k(const float* __restrict__ x, const float* __restrict__ sh,
            _Float16* __restrict__ Bp, float* __restrict__ invn,
            float* __restrict__ out) {
    __shared__ float xr[L_];             // norm blocks only
    const int tid = threadIdx.x;
    const int blk = blockIdx.x;

    if (blk < 128) {
        const int sb   = blk * 4 + (tid >> 6);   // 0..511 = c(8) x kq(4) x nt(16)
        const int c    = sb >> 6;
        const int kq   = (sb >> 4) & 3;
        const int nt   = sb & 15;
        const int lane = tid & 63;
        const int n    = lane & 31;
        const int half = lane >> 5;
        const int q    = nt * 32 + n;

        const float4* sp = (const float4*)(sh + (size_t)(c * K_ + q) * S_);
        float ss = 0.f;
        #pragma unroll
        for (int i = 0; i < 8; ++i) {
            float4 v = sp[half * 8 + i];
            ss += v.x * v.x + v.y * v.y + v.z * v.z + v.w * v.w;
        }
        ss += __shfl_xor(ss, 32);        // combine the two 32-elem halves of q
        float inv = 1.f / fmaxf(sqrtf(ss), 1e-8f);

        float4 u0 = sp[kq * 4 + half * 2];
        float4 u1 = sp[kq * 4 + half * 2 + 1];
        f16x8 o;
        o[0] = (_Float16)(u0.x * inv); o[1] = (_Float16)(u0.y * inv);
        o[2] = (_Float16)(u0.z * inv); o[3] = (_Float16)(u0.w * inv);
        o[4] = (_Float16)(u1.x * inv); o[5] = (_Float16)(u1.y * inv);
        o[6] = (_Float16)(u1.z * inv); o[7] = (_Float16)(u1.w * inv);
        ((f16x8*)Bp)[((c * 4 + kq) * 16 + nt) * 64 + lane] = o;
    } else {
        // window inverse norms for row r = b*8+c via sliding sum
        const int r = blk - 128;             // 0..255
        const float* xp = x + (size_t)r * L_;
        for (int i = tid; i < L_ / 4; i += 256)
            ((float4*)xr)[i] = ((const float4*)xp)[i];
        __syncthreads();

        float* ivp = invn + (size_t)r * L_;
        const int w0 = tid * 8;
        float ss = 0.f;
        if (w0 < W_) {
            #pragma unroll
            for (int j = 0; j < S_; ++j) { float v = xr[w0 + j]; ss += v * v; }
        }
        #pragma unroll
        for (int u = 0; u < 8; ++u) {
            int w = w0 + u;
            float o = 0.f;
            if (u > 0 && w < W_)
                ss += xr[w + 63] * xr[w + 63] - xr[w - 1] * xr[w - 1];
            if (w < W_) o = 0.125f / fmaxf(sqrtf(ss), 1e-8f);
            if (w < L_) ivp[w] = o;
        }
        if (r < 64) out[r * 256 + tid] = 0.f;   // zero output
    }
}

// ---- main: 32x32x16 MFMA GEMM + relu + max ----
// grid (32 wt, 2 ng, 32 b), 256 threads = 4 waves.
// Block: 64 windows x 256 cols. Wave wv: 64 windows (mt=2) x 64 cols (nt=2).
// acc = 2x2 x f32x16 = 64 VGPRs. Channels processed in PAIRS, double-buffered
// A-frag LDS (2 x 16 KB), one barrier per pair -> 6 barriers total.
__global__ __launch_bounds__(256, 3)
void mcs_k(const float* __restrict__ x, const _Float16* __restrict__ Bp,
           const float* __restrict__ invn, float* __restrict__ out) {
    __shared__ float invs[C_ * TW];      // 2 KB
    __shared__ f16x8 Ah[2][16 * 64];     // 32 KB: 16 frags (ch2 x mt2 x ks4) x 64 lanes

    const int wt  = blockIdx.x;
    const int ng  = blockIdx.y;
    const int b   = blockIdx.z;
    const int w0  = wt * TW;
    const int tid = threadIdx.x;
    const int lane = tid & 63;
    const int wv   = tid >> 6;

    // stage inv-norm slice (0.125/||win||, 0 for invalid windows)
    for (int i = tid; i < C_ * TW; i += 256) {
        int c = i >> 6, w = i & 63;
        invs[i] = invn[(size_t)(b * C_ + c) * L_ + w0 + w];
    }

    // build A-frags for channel pair cp into Ah[buf].
    // frag f = ch*8 + mt*4 + ks; lane l: A[m=l&31][k=ks*16+(l>>5)*8+j]
    auto build = [&](int cp, int buf) {
        const int c0 = cp * 2;
        #pragma unroll
        for (int it = 0; it < 4; ++it) {
            int i  = tid + it * 256;        // 0..1023
            int f  = i >> 6, l = i & 63;
            int ch = f >> 3, mt = (f >> 2) & 1, ks = f & 3;
            int m  = mt * 32 + (l & 31);
            int p  = w0 + m + ks * 16 + (l >> 5) * 8;
            int pc = p <= L_ - 8 ? p : L_ - 8;   // only invalid windows clamp
            const float* xrow = x + (size_t)(b * C_ + c0 + ch) * L_;
            f32x4u v0 = *(const f32x4u*)(xrow + pc);
            f32x4u v1 = *(const f32x4u*)(xrow + pc + 4);
            float iv = invs[(c0 + ch) * TW + m];  // 0 for invalid windows
            f16x8 o;
            o[0] = (_Float16)(v0[0] * iv); o[1] = (_Float16)(v0[1] * iv);
            o[2] = (_Float16)(v0[2] * iv); o[3] = (_Float16)(v0[3] * iv);
            o[4] = (_Float16)(v1[0] * iv); o[5] = (_Float16)(v1[1] * iv);
            o[6] = (_Float16)(v1[2] * iv); o[7] = (_Float16)(v1[3] * iv);
            Ah[buf][f * 64 + l] = o;
        }
    };

    __syncthreads();            // invs ready
    build(0, 0);
    __syncthreads();            // Ah[0] ready

    f32x16 acc[2][2];
    #pragma unroll
    for (int mt = 0; mt < 2; ++mt)
        #pragma unroll
        for (int nt = 0; nt < 2; ++nt)
            #pragma unroll
            for (int r = 0; r < 16; ++r) acc[mt][nt][r] = 0.f;

    #pragma unroll 1
    for (int cp = 0; cp < 4; ++cp) {
        const int buf = cp & 1;
        if (cp + 1 < 4) build(cp + 1, buf ^ 1);   // prefetch next pair

        #pragma unroll
        for (int ch = 0; ch < 2; ++ch) {
            const int c = cp * 2 + ch;
            #pragma unroll
            for (int ks = 0; ks < 4; ++ks) {
                f16x8 af[2], bf[2];
                #pragma unroll
                for (int mt = 0; mt < 2; ++mt)
                    af[mt] = Ah[buf][(ch * 8 + mt * 4 + ks) * 64 + lane];
                const f16x8* bpp = (const f16x8*)Bp +
                    ((c * 4 + ks) * 16 + ng * 8 + wv * 2) * 64 + lane;
                #pragma unroll
                for (int nt = 0; nt < 2; ++nt) bf[nt] = bpp[nt * 64];
                #pragma unroll
                for (int nt = 0; nt < 2; ++nt)
                    #pragma unroll
                    for (int mt = 0; mt < 2; ++mt)
                        acc[mt][nt] = __builtin_amdgcn_mfma_f32_32x32x16_f16(
                            af[mt], bf[nt], acc[mt][nt], 0, 0, 0);
            }
        }
        __syncthreads();        // consume(cp) done + Ah[buf^1] written
    }

    // epilogue: relu + max over windows (invalid windows exactly 0).
    // 32x32 C/D: col = lane&31 (lane and lane+32 share a col) -> only col needed.
    #pragma unroll
    for (int nt = 0; nt < 2; ++nt) {
        float m = 0.f;
        #pragma unroll
        for (int mt = 0; mt < 2; ++mt)
            #pragma unroll
            for (int r = 0; r < 16; ++r)
                m = fmaxf(m, acc[mt][nt][r]);
        m = fmaxf(m, __shfl_xor(m, 32));
        if (lane < 32)
            atomicMax((unsigned int*)(out + b * K_ + ng * 256 + wv * 64 + nt * 32 + lane),
                      __float_as_uint(m));
    }
}

extern "C" void kernel_launch(void* const* d_in, const int* in_sizes, int n_in,
                              void* d_out, int out_size, void* d_ws, size_t ws_size,
                              hipStream_t stream) {
    const float* x  = (const float*)d_in[0];   // (32, 8, 2048) fp32
    const float* sh = (const float*)d_in[1];   // (8, 512, 64) fp32
    float* out = (float*)d_out;                // (32, 1, 512) fp32
    _Float16* Bp  = (_Float16*)d_ws;           // 512 KB packed shapelets
    float* invn   = (float*)((char*)d_ws + (size_t)K_ * 512 * sizeof(_Float16)); // 2 MB

    prep_k<<<dim3(384), dim3(256), 0, stream>>>(x, sh, Bp, invn, out);
    mcs_k<<<dim3(32, 2, B_), dim3(256), 0, stream>>>(x, Bp, invn, out);
}